// Round 3
// baseline (730.385 us; speedup 1.0000x reference)
//
#include <hip/hip_runtime.h>
#include <hip/hip_bf16.h>
#include <stdint.h>

#define NN   100000
#define NE   1600000
#define FIN  128
#define FOUT 200
#define NBLK 391   // ceil(NN/256)

typedef __attribute__((ext_vector_type(8))) short short8;
typedef __attribute__((ext_vector_type(4))) float f32x4;

__device__ __forceinline__ short f2bf(float f) {
    __hip_bfloat16 h = __float2bfloat16(f);
    return *reinterpret_cast<short*>(&h);
}

__device__ __forceinline__ int getidx(const void* ei, int isI32, long long i) {
    return isI32 ? ((const int*)ei)[i] : (int)((const long long*)ei)[i];
}

// --- dtype detection: read edge_index as int64; if any value out of [0,NN), it is int32 ---
__global__ void detect_kernel(const long long* ei64, int* flag) {
    int t = blockIdx.x * blockDim.x + threadIdx.x;   // 4096 samples
    long long v = ei64[t];
    if (v < 0 || v >= NN) atomicOr(flag, 1);
}

// deg[r] += w ; cnt[r] += 1   (fused)
__global__ void deg_count_kernel(const void* ei, const int* flag, const float* w,
                                 float* deg, int* cnt) {
    int e = blockIdx.x * blockDim.x + threadIdx.x;   // NE exact
    int r = getidx(ei, *flag, e);
    atomicAdd(&deg[r], w[e]);
    atomicAdd(&cnt[r], 1);
}

// hierarchical exclusive scan of cnt -> rowstart
__global__ void scan_block(const int* __restrict__ cnt, int* __restrict__ rowstart,
                           int* __restrict__ bsum) {
    __shared__ int tmp[256];
    int i = blockIdx.x * 256 + threadIdx.x;
    int v = (i < NN) ? cnt[i] : 0;
    tmp[threadIdx.x] = v;
    __syncthreads();
    for (int off = 1; off < 256; off <<= 1) {
        int t = (threadIdx.x >= off) ? tmp[threadIdx.x - off] : 0;
        __syncthreads();
        tmp[threadIdx.x] += t;
        __syncthreads();
    }
    if (i < NN) rowstart[i] = tmp[threadIdx.x] - v;   // block-local exclusive
    if (threadIdx.x == 255) bsum[blockIdx.x] = tmp[255];
}

__global__ void scan_bsums(int* bsum) {   // 1 block, 512 threads
    __shared__ int tmp[512];
    int t = threadIdx.x;
    int v = (t < NBLK) ? bsum[t] : 0;
    tmp[t] = v;
    __syncthreads();
    for (int off = 1; off < 512; off <<= 1) {
        int u = (t >= off) ? tmp[t - off] : 0;
        __syncthreads();
        tmp[t] += u;
        __syncthreads();
    }
    if (t < NBLK) bsum[t] = tmp[t] - v;   // exclusive
}

__global__ void scan_add(int* __restrict__ rowstart, const int* __restrict__ bsum,
                         int* __restrict__ cnt) {
    int i = blockIdx.x * 256 + threadIdx.x;   // covers NN+1
    if (i < NN) {
        rowstart[i] += bsum[i >> 8];
        cnt[i] = 0;                 // reuse cnt as fill counter
    } else if (i == NN) {
        rowstart[NN] = NE;
    }
}

// counting-sort edges by destination row; compute norm inline
__global__ void fill_csr(const void* ei, const int* flag, const float* __restrict__ w,
                         const float* __restrict__ deg, const int* __restrict__ rowstart,
                         int* __restrict__ fill, int* __restrict__ ecol,
                         float* __restrict__ enorm) {
    int e = blockIdx.x * blockDim.x + threadIdx.x;   // NE exact
    int isI32 = *flag;
    int r = getidx(ei, isI32, e);
    int c = getidx(ei, isI32, (long long)NE + e);
    float dr = deg[r], dc = deg[c];
    float ir = dr > 0.f ? rsqrtf(dr) : 0.f;
    float ic = dc > 0.f ? rsqrtf(dc) : 0.f;
    int pos = rowstart[r] + atomicAdd(&fill[r], 1);
    ecol[pos] = c;
    enorm[pos] = -w[e] * ir * ic;
}

// one wave per destination row; MODE 0: dst = P(src); MODE 1: dst = 2*P(src) - x
template <int MODE>
__launch_bounds__(256)
__global__ void gather_prop(const int* __restrict__ rowstart, const int* __restrict__ ecol,
                            const float* __restrict__ enorm, const float* __restrict__ src,
                            const float* __restrict__ x, float* __restrict__ dst) {
    int gw   = (blockIdx.x << 2) + (threadIdx.x >> 6);   // global wave = row
    int lane = threadIdx.x & 63;
    int s = rowstart[gw], eend = rowstart[gw + 1];
    const float2* srcp = (const float2*)src;
    float ax = 0.f, ay = 0.f;
    int e = s;
    for (; e + 1 < eend; e += 2) {
        int c0 = ecol[e];     float w0 = enorm[e];
        int c1 = ecol[e + 1]; float w1 = enorm[e + 1];
        float2 v0 = srcp[(c0 << 6) + lane];
        float2 v1 = srcp[(c1 << 6) + lane];
        ax += w0 * v0.x; ay += w0 * v0.y;
        ax += w1 * v1.x; ay += w1 * v1.y;
    }
    if (e < eend) {
        int c0 = ecol[e]; float w0 = enorm[e];
        float2 v0 = srcp[(c0 << 6) + lane];
        ax += w0 * v0.x; ay += w0 * v0.y;
    }
    float2 o;
    if (MODE == 1) {
        float2 xv = ((const float2*)x)[(gw << 6) + lane];
        o.x = 2.f * ax - xv.x;
        o.y = 2.f * ay - xv.y;
    } else {
        o.x = ax; o.y = ay;
    }
    ((float2*)dst)[(gw << 6) + lane] = o;
}

// ---------------------------------------------------------------------------
// Weight prep: pack W into MFMA B-fragment order.
// Frag unit = (tile t, kstep ks): 64 lanes x 8 bf16 = 512 shorts (1 KB).
// Unit index within scale s: t*nk + ks  (nk = (s+1)*4).  Scale base fb(s) =
// {0, 52, 156} units.  Lane l holds B[col = t*16 + (l&15)][k = ks*32 + (l>>4)*8 + i]
// where B[c][k] = W_s[k][c].
// One block per global kstep (24 blocks): LDS-transpose 32x200 panel slice.
// ---------------------------------------------------------------------------
__global__ void wprep_frag(const float* __restrict__ W1, const float* __restrict__ W2,
                           const float* __restrict__ W3, short* __restrict__ Wf) {
    __shared__ float lds[32 * 200];
    int bid = blockIdx.x;
    int s, ks;
    if (bid < 4)       { s = 0; ks = bid; }
    else if (bid < 12) { s = 1; ks = bid - 4; }
    else               { s = 2; ks = bid - 12; }
    const float* W = (s == 0) ? W1 : ((s == 1) ? W2 : W3);
    int p = ks >> 2;
    const float* Wp = W + (p * 128 + (ks & 3) * 32) * 200;   // [32][200] slice, contiguous
    for (int e = threadIdx.x; e < 6400; e += 256) lds[e] = Wp[e];
    __syncthreads();
    int nk = (s + 1) * 4;
    int fb = (s == 0) ? 0 : ((s == 1) ? 52 : 156);
    for (int q = threadIdx.x; q < 13 * 64; q += 256) {
        int t = q >> 6, lane = q & 63;
        int col = t * 16 + (lane & 15);
        int kb  = (lane >> 4) * 8;
        short8 v;
        #pragma unroll
        for (int i = 0; i < 8; ++i) {
            float f = (col < FOUT) ? lds[(kb + i) * 200 + col] : 0.f;
            v[i] = f2bf(f);
        }
        *(short8*)&Wf[(fb + t * nk + ks) * 512 + lane * 8] = v;
    }
}

// ---------------------------------------------------------------------------
// LDS-free GEMM: out_s[n,:] = sum_panels T_p[n] @ W_s[p] + b_s.
// 256 threads = 4 waves, 32 rows/wave (2 MFMA row-frags), BM=128.
// A-frags straight from global fp32 (LLC-resident), converted to bf16 in-reg.
// B-frags from pre-packed Wf (coalesced 1KB loads, L2-resident).
// ---------------------------------------------------------------------------
__launch_bounds__(256)
__global__ void gemm_kernel(const float* __restrict__ x, const float* __restrict__ t1,
                            const float* __restrict__ t2, const short* __restrict__ Wf,
                            const float* __restrict__ b1, const float* __restrict__ b2,
                            const float* __restrict__ b3, float* __restrict__ out) {
    const int s    = blockIdx.y;
    const int n0   = blockIdx.x * 128;
    const int wave = threadIdx.x >> 6;
    const int lane = threadIdx.x & 63;
    const int l15  = lane & 15;
    const int lhi  = lane >> 4;

    const float* panels[3] = {x, t1, t2};
    const int nk = (s + 1) * 4;
    const int fb = (s == 0) ? 0 : ((s == 1) ? 52 : 156);

    // A rows for this wave's two 16-row fragments (clamped for tail block)
    int r0 = n0 + wave * 32 + l15;
    int r1 = r0 + 16;
    const int lr0 = (r0 < NN) ? r0 : 0;
    const int lr1 = (r1 < NN) ? r1 : 0;

    f32x4 acc[2][13];
    #pragma unroll
    for (int m = 0; m < 2; ++m)
        #pragma unroll
        for (int t = 0; t < 13; ++t) acc[m][t] = {0.f, 0.f, 0.f, 0.f};

    const short* wbase = Wf + (long long)(fb) * 512 + lane * 8;

    for (int p = 0; p <= s; ++p) {
        const float* src = panels[p];
        const float* a0p = src + (long long)lr0 * FIN + lhi * 8;
        const float* a1p = src + (long long)lr1 * FIN + lhi * 8;
        #pragma unroll
        for (int k4 = 0; k4 < 4; ++k4) {
            const int kk = k4 * 32;
            f32x4 u0 = *(const f32x4*)(a0p + kk);
            f32x4 u1 = *(const f32x4*)(a0p + kk + 4);
            f32x4 v0 = *(const f32x4*)(a1p + kk);
            f32x4 v1 = *(const f32x4*)(a1p + kk + 4);
            short8 a0, a1;
            #pragma unroll
            for (int i = 0; i < 4; ++i) {
                a0[i] = f2bf(u0[i]); a0[4 + i] = f2bf(u1[i]);
                a1[i] = f2bf(v0[i]); a1[4 + i] = f2bf(v1[i]);
            }
            const int ks = p * 4 + k4;
            const short* bp = wbase + ks * 512;
            #pragma unroll
            for (int t = 0; t < 13; ++t) {
                short8 b = *(const short8*)(bp + t * nk * 512);
                acc[0][t] = __builtin_amdgcn_mfma_f32_16x16x32_bf16(a0, b, acc[0][t], 0, 0, 0);
                acc[1][t] = __builtin_amdgcn_mfma_f32_16x16x32_bf16(a1, b, acc[1][t], 0, 0, 0);
            }
        }
    }

    const float* bias = (s == 0) ? b1 : ((s == 1) ? b2 : b3);
    float* outp = out + (long long)s * NN * FOUT;
    #pragma unroll
    for (int t = 0; t < 13; ++t) {
        int col = t * 16 + l15;
        if (col < FOUT) {
            float bv = bias[col];
            #pragma unroll
            for (int m = 0; m < 2; ++m) {
                int rbase = n0 + wave * 32 + m * 16 + lhi * 4;
                #pragma unroll
                for (int j = 0; j < 4; ++j) {
                    int r = rbase + j;
                    if (r < NN) outp[(long long)r * FOUT + col] = acc[m][t][j] + bv;
                }
            }
        }
    }
}

extern "C" void kernel_launch(void* const* d_in, const int* in_sizes, int n_in,
                              void* d_out, int out_size, void* d_ws, size_t ws_size,
                              hipStream_t stream) {
    const float* x  = (const float*)d_in[0];
    const void*  ei = d_in[1];
    const float* ew = (const float*)d_in[2];
    const float* W1 = (const float*)d_in[3];
    const float* b1 = (const float*)d_in[4];
    const float* W2 = (const float*)d_in[5];
    const float* b2 = (const float*)d_in[6];
    const float* W3 = (const float*)d_in[7];
    const float* b3 = (const float*)d_in[8];
    float* out = (float*)d_out;

    char* ws = (char*)d_ws;
    // layout (bytes):
    // [0,16)                flag
    // [16, 400016)          deg      (N f32)         } zeroed
    // [400016, 800016)      cnt/fill (N i32)         } zeroed
    // [800016, 1200020)     rowstart (N+1 i32)
    // [1200032, 1202080)    bsum     (512 i32)
    // [1202080, 7602080)    ecol     (E i32)
    // [7602080, 14002080)   enorm    (E f32)
    // [14002080, 65202080)  T1       (N*128 f32)
    // [65202080, 116402080) T2       (N*128 f32)
    // [116402080, ...)      Wf       (bf16 frags, 312*512 shorts = 319488 B)
    int*   flag     = (int*)(ws + 0);
    float* deg      = (float*)(ws + 16);
    int*   cnt      = (int*)(ws + 400016);
    int*   rowstart = (int*)(ws + 800016);
    int*   bsum     = (int*)(ws + 1200032);
    int*   ecol     = (int*)(ws + 1202080);
    float* enorm    = (float*)(ws + 7602080);
    float* T1       = (float*)(ws + 14002080);
    float* T2       = (float*)(ws + 65202080);
    short* Wf       = (short*)(ws + 116402080);

    hipMemsetAsync(d_ws, 0, 800016, stream);   // flag + deg + cnt

    detect_kernel<<<16, 256, 0, stream>>>((const long long*)ei, flag);
    deg_count_kernel<<<NE / 256, 256, 0, stream>>>(ei, flag, ew, deg, cnt);
    scan_block<<<NBLK, 256, 0, stream>>>(cnt, rowstart, bsum);
    scan_bsums<<<1, 512, 0, stream>>>(bsum);
    scan_add<<<NBLK + 1, 256, 0, stream>>>(rowstart, bsum, cnt);
    fill_csr<<<NE / 256, 256, 0, stream>>>(ei, flag, ew, deg, rowstart, cnt, ecol, enorm);
    gather_prop<0><<<NN / 4, 256, 0, stream>>>(rowstart, ecol, enorm, x, nullptr, T1);
    gather_prop<1><<<NN / 4, 256, 0, stream>>>(rowstart, ecol, enorm, T1, x, T2);
    wprep_frag<<<24, 256, 0, stream>>>(W1, W2, W3, Wf);
    gemm_kernel<<<dim3(782, 3), 256, 0, stream>>>(x, T1, T2, Wf, b1, b2, b3, out);
}

// Round 4
// 729.210 us; speedup vs baseline: 1.0016x; 1.0016x over previous
//
#include <hip/hip_runtime.h>
#include <hip/hip_bf16.h>
#include <stdint.h>

#define NN    100000
#define NROWP 100096   // padded rows (gemm tail reads up to 100031)
#define NE    1600000
#define FIN   128
#define FOUT  200
#define NBLK  391      // ceil(NN/256)

typedef __attribute__((ext_vector_type(8))) short short8;
typedef __attribute__((ext_vector_type(8))) unsigned short ushort8;
typedef __attribute__((ext_vector_type(4))) float f32x4;
typedef __attribute__((ext_vector_type(4))) unsigned int uint32x4;

__device__ __forceinline__ short f2bf(float f) {
    __hip_bfloat16 h = __float2bfloat16(f);
    return *reinterpret_cast<short*>(&h);
}
__device__ __forceinline__ unsigned short f2bfu(float f) {
    __hip_bfloat16 h = __float2bfloat16(f);
    return *reinterpret_cast<unsigned short*>(&h);
}
__device__ __forceinline__ float bf2f(unsigned short u) {
    return __uint_as_float((unsigned)u << 16);
}
__device__ __forceinline__ int getidx(const void* ei, int isI32, long long i) {
    return isI32 ? ((const int*)ei)[i] : (int)((const long long*)ei)[i];
}

// --- dtype detection: read edge_index as int64; if any value out of [0,NN), it is int32 ---
__global__ void detect_kernel(const long long* ei64, int* flag) {
    int t = blockIdx.x * blockDim.x + threadIdx.x;   // 4096 samples
    long long v = ei64[t];
    if (v < 0 || v >= NN) atomicOr(flag, 1);
}

__global__ void x2bf_kernel(const float* __restrict__ x, unsigned short* __restrict__ xb) {
    long long i = ((long long)blockIdx.x * 256 + threadIdx.x) * 8;   // NN*FIN exact
    f32x4 v0 = *(const f32x4*)(x + i);
    f32x4 v1 = *(const f32x4*)(x + i + 4);
    ushort8 o;
    #pragma unroll
    for (int k = 0; k < 4; ++k) { o[k] = f2bfu(v0[k]); o[4 + k] = f2bfu(v1[k]); }
    *(ushort8*)(xb + i) = o;
}

// deg[r] += w ; cnt[r] += 1   (fused)
__global__ void deg_count_kernel(const void* ei, const int* flag, const float* w,
                                 float* deg, int* cnt) {
    int e = blockIdx.x * blockDim.x + threadIdx.x;   // NE exact
    int r = getidx(ei, *flag, e);
    atomicAdd(&deg[r], w[e]);
    atomicAdd(&cnt[r], 1);
}

// hierarchical exclusive scan of cnt -> rowstart
__global__ void scan_block(const int* __restrict__ cnt, int* __restrict__ rowstart,
                           int* __restrict__ bsum) {
    __shared__ int tmp[256];
    int i = blockIdx.x * 256 + threadIdx.x;
    int v = (i < NN) ? cnt[i] : 0;
    tmp[threadIdx.x] = v;
    __syncthreads();
    for (int off = 1; off < 256; off <<= 1) {
        int t = (threadIdx.x >= off) ? tmp[threadIdx.x - off] : 0;
        __syncthreads();
        tmp[threadIdx.x] += t;
        __syncthreads();
    }
    if (i < NN) rowstart[i] = tmp[threadIdx.x] - v;
    if (threadIdx.x == 255) bsum[blockIdx.x] = tmp[255];
}

__global__ void scan_bsums(int* bsum) {   // 1 block, 512 threads
    __shared__ int tmp[512];
    int t = threadIdx.x;
    int v = (t < NBLK) ? bsum[t] : 0;
    tmp[t] = v;
    __syncthreads();
    for (int off = 1; off < 512; off <<= 1) {
        int u = (t >= off) ? tmp[t - off] : 0;
        __syncthreads();
        tmp[t] += u;
        __syncthreads();
    }
    if (t < NBLK) bsum[t] = tmp[t] - v;
}

__global__ void scan_add(int* __restrict__ rowstart, const int* __restrict__ bsum,
                         int* __restrict__ cnt) {
    int i = blockIdx.x * 256 + threadIdx.x;
    if (i < NN) {
        rowstart[i] += bsum[i >> 8];
        cnt[i] = 0;                 // reuse cnt as fill counter
    } else if (i == NN) {
        rowstart[NN] = NE;
    }
}

// counting-sort edges by destination row; edge record = {col, norm_bits}
__global__ void fill_csr(const void* ei, const int* flag, const float* __restrict__ w,
                         const float* __restrict__ deg, const int* __restrict__ rowstart,
                         int* __restrict__ fill, int2* __restrict__ edge) {
    int e = blockIdx.x * blockDim.x + threadIdx.x;   // NE exact
    int isI32 = *flag;
    int r = getidx(ei, isI32, e);
    int c = getidx(ei, isI32, (long long)NE + e);
    float dr = deg[r], dc = deg[c];
    float ir = dr > 0.f ? rsqrtf(dr) : 0.f;
    float ic = dc > 0.f ? rsqrtf(dc) : 0.f;
    int pos = rowstart[r] + atomicAdd(&fill[r], 1);
    int2 rec; rec.x = c; rec.y = __float_as_int(-w[e] * ir * ic);
    edge[pos] = rec;
}

// one wave per destination row, quarter-wave per edge, bf16 rows (256B).
// MODE 0: dst = P(src); MODE 1: dst = 2*P(src) - x
template <int MODE>
__launch_bounds__(256)
__global__ void gather_prop(const int* __restrict__ rowstart, const int2* __restrict__ edge,
                            const unsigned short* __restrict__ srcb,
                            const unsigned short* __restrict__ xb,
                            unsigned short* __restrict__ dstb) {
    int gw   = (blockIdx.x << 2) + (threadIdx.x >> 6);   // row
    int lane = threadIdx.x & 63;
    int q = lane >> 4, fl = lane & 15;                   // quarter, 16B chunk
    int s = rowstart[gw], eend = rowstart[gw + 1];
    float a[8] = {0.f,0.f,0.f,0.f,0.f,0.f,0.f,0.f};
    for (int e = s + q; e < eend; e += 4) {
        int2 ed = edge[e];
        float w = __int_as_float(ed.y);
        ushort8 v = *(const ushort8*)(srcb + ((long long)ed.x << 7) + (fl << 3));
        #pragma unroll
        for (int i = 0; i < 8; ++i) a[i] += w * bf2f(v[i]);
    }
    #pragma unroll
    for (int i = 0; i < 8; ++i) {
        a[i] += __shfl_xor(a[i], 16);
        a[i] += __shfl_xor(a[i], 32);
    }
    if (lane < 16) {
        ushort8 o;
        if (MODE == 1) {
            ushort8 xv = *(const ushort8*)(xb + ((long long)gw << 7) + (fl << 3));
            #pragma unroll
            for (int i = 0; i < 8; ++i) o[i] = f2bfu(2.f * a[i] - bf2f(xv[i]));
        } else {
            #pragma unroll
            for (int i = 0; i < 8; ++i) o[i] = f2bfu(a[i]);
        }
        *(ushort8*)(dstb + ((long long)gw << 7) + (fl << 3)) = o;
    }
}

// ---------------------------------------------------------------------------
// Weight prep: pack W into MFMA B-fragment order (unchanged from round 3).
// Frag unit (tile t, kstep ks) of scale s at unit index fb(s) + t*nk + ks,
// nk = 4(s+1), fb = {0, 52, 156}.  Lane l holds W_s[k=ks*32+(l>>4)*8+i][col=t*16+(l&15)].
// ---------------------------------------------------------------------------
__global__ void wprep_frag(const float* __restrict__ W1, const float* __restrict__ W2,
                           const float* __restrict__ W3, short* __restrict__ Wf) {
    __shared__ float lds[32 * 200];
    int bid = blockIdx.x;
    int s, ks;
    if (bid < 4)       { s = 0; ks = bid; }
    else if (bid < 12) { s = 1; ks = bid - 4; }
    else               { s = 2; ks = bid - 12; }
    const float* W = (s == 0) ? W1 : ((s == 1) ? W2 : W3);
    int p = ks >> 2;
    const float* Wp = W + (p * 128 + (ks & 3) * 32) * 200;
    for (int e = threadIdx.x; e < 6400; e += 256) lds[e] = Wp[e];
    __syncthreads();
    int nk = (s + 1) * 4;
    int fb = (s == 0) ? 0 : ((s == 1) ? 52 : 156);
    for (int qq = threadIdx.x; qq < 13 * 64; qq += 256) {
        int t = qq >> 6, lane = qq & 63;
        int col = t * 16 + (lane & 15);
        int kb  = (lane >> 4) * 8;
        short8 v;
        #pragma unroll
        for (int i = 0; i < 8; ++i) {
            float f = (col < FOUT) ? lds[(kb + i) * 200 + col] : 0.f;
            v[i] = f2bf(f);
        }
        *(short8*)&Wf[(fb + t * nk + ks) * 512 + lane * 8] = v;
    }
}

// ---------------------------------------------------------------------------
// Fused all-scales GEMM, zero barriers. 4 waves, 16 rows/wave, BM=64.
// Per wave: stage own 16 bf16 rows of panel p into private swizzled LDS,
// then 4 ksteps x (1 ds_read_b128 A-frag + per-tile B-frag global load + MFMA).
// acc[39] covers 3 scales x 13 col-tiles.
// ---------------------------------------------------------------------------
__launch_bounds__(256, 2)
__global__ void gemm_kernel(const unsigned short* __restrict__ xb,
                            const unsigned short* __restrict__ t1b,
                            const unsigned short* __restrict__ t2b,
                            const short* __restrict__ Wf,
                            const float* __restrict__ b1, const float* __restrict__ b2,
                            const float* __restrict__ b3, float* __restrict__ out) {
    __shared__ short As[4][16][128];   // 16KB, per-wave private
    const int wave = threadIdx.x >> 6;
    const int lane = threadIdx.x & 63;
    const int l15  = lane & 15;
    const int lhi  = lane >> 4;
    const int wr0  = blockIdx.x * 64 + wave * 16;

    f32x4 acc[39];
    #pragma unroll
    for (int g = 0; g < 39; ++g) acc[g] = {0.f, 0.f, 0.f, 0.f};

    const unsigned short* panels[3] = {xb, t1b, t2b};
    short* myA = &As[wave][0][0];
    const int srow = lane >> 2, schunk = lane & 3;   // stage: 16 rows x 4 chunks(64B)
    const int rs = srow & 7;

    #pragma unroll
    for (int p = 0; p < 3; ++p) {
        const unsigned short* src = panels[p] + ((long long)(wr0 + srow) << 7) + (schunk << 5);
        uint32x4 c0 = *(const uint32x4*)(src);
        uint32x4 c1 = *(const uint32x4*)(src + 8);
        uint32x4 c2 = *(const uint32x4*)(src + 16);
        uint32x4 c3 = *(const uint32x4*)(src + 24);
        int wb = srow * 128;
        *(uint32x4*)(myA + wb + ((((schunk << 2) + 0) ^ rs) << 3)) = c0;
        *(uint32x4*)(myA + wb + ((((schunk << 2) + 1) ^ rs) << 3)) = c1;
        *(uint32x4*)(myA + wb + ((((schunk << 2) + 2) ^ rs) << 3)) = c2;
        *(uint32x4*)(myA + wb + ((((schunk << 2) + 3) ^ rs) << 3)) = c3;
        #pragma unroll
        for (int k4 = 0; k4 < 4; ++k4) {
            short8 afrag = *(const short8*)(myA + l15 * 128 + ((((k4 << 2) + lhi) ^ (l15 & 7)) << 3));
            #pragma unroll
            for (int g = 0; g < 39; ++g) {
                const int sc = g / 13;
                if (sc < p) continue;
                const int tt = g % 13;
                const int nk = 4 * (sc + 1);
                const int fb = (sc == 0) ? 0 : ((sc == 1) ? 52 : 156);
                const int u  = fb + tt * nk + (p * 4 + k4);
                short8 bfrag = *(const short8*)(Wf + (long long)u * 512 + lane * 8);
                acc[g] = __builtin_amdgcn_mfma_f32_16x16x32_bf16(afrag, bfrag, acc[g], 0, 0, 0);
            }
        }
    }

    #pragma unroll
    for (int g = 0; g < 39; ++g) {
        const int sc = g / 13, tt = g % 13;
        const int col = tt * 16 + l15;
        if (col < FOUT) {
            const float* bias = (sc == 0) ? b1 : ((sc == 1) ? b2 : b3);
            float bv = bias[col];
            float* outp = out + (long long)sc * NN * FOUT;
            const int rbase = wr0 + lhi * 4;
            #pragma unroll
            for (int j = 0; j < 4; ++j) {
                int r = rbase + j;
                if (r < NN) outp[(long long)r * FOUT + col] = acc[g][j] + bv;
            }
        }
    }
}

extern "C" void kernel_launch(void* const* d_in, const int* in_sizes, int n_in,
                              void* d_out, int out_size, void* d_ws, size_t ws_size,
                              hipStream_t stream) {
    const float* x  = (const float*)d_in[0];
    const void*  ei = d_in[1];
    const float* ew = (const float*)d_in[2];
    const float* W1 = (const float*)d_in[3];
    const float* b1 = (const float*)d_in[4];
    const float* W2 = (const float*)d_in[5];
    const float* b2 = (const float*)d_in[6];
    const float* W3 = (const float*)d_in[7];
    const float* b3 = (const float*)d_in[8];
    float* out = (float*)d_out;

    char* ws = (char*)d_ws;
    // layout (bytes):
    // [0,16)                 flag        } zeroed
    // [16, 400016)           deg  N f32  } zeroed
    // [400016, 800016)       cnt  N i32  } zeroed
    // [800016, 1200020)      rowstart N+1
    // [1200032, 1202080)     bsum 512
    // [1202080, 14002080)    edge int2 E
    // [14002080, 39626656)   Xb  bf16 NROWP*128
    // [39626656, 65251232)   T1b bf16
    // [65251232, 90875808)   T2b bf16
    // [90875808, 91195296)   Wf  bf16 frags (312 KB)
    int*   flag     = (int*)(ws + 0);
    float* deg      = (float*)(ws + 16);
    int*   cnt      = (int*)(ws + 400016);
    int*   rowstart = (int*)(ws + 800016);
    int*   bsum     = (int*)(ws + 1200032);
    int2*  edge     = (int2*)(ws + 1202080);
    unsigned short* Xb  = (unsigned short*)(ws + 14002080);
    unsigned short* T1b = (unsigned short*)(ws + 39626656);
    unsigned short* T2b = (unsigned short*)(ws + 65251232);
    short* Wf       = (short*)(ws + 90875808);

    hipMemsetAsync(d_ws, 0, 800016, stream);   // flag + deg + cnt

    detect_kernel<<<16, 256, 0, stream>>>((const long long*)ei, flag);
    x2bf_kernel<<<6250, 256, 0, stream>>>(x, Xb);
    deg_count_kernel<<<NE / 256, 256, 0, stream>>>(ei, flag, ew, deg, cnt);
    scan_block<<<NBLK, 256, 0, stream>>>(cnt, rowstart, bsum);
    scan_bsums<<<1, 512, 0, stream>>>(bsum);
    scan_add<<<NBLK + 1, 256, 0, stream>>>(rowstart, bsum, cnt);
    fill_csr<<<NE / 256, 256, 0, stream>>>(ei, flag, ew, deg, rowstart, cnt, edge);
    gather_prop<0><<<NN / 4, 256, 0, stream>>>(rowstart, edge, Xb, nullptr, T1b);
    gather_prop<1><<<NN / 4, 256, 0, stream>>>(rowstart, edge, T1b, Xb, T2b);
    wprep_frag<<<24, 256, 0, stream>>>(W1, W2, W3, Wf);
    gemm_kernel<<<1563, 256, 0, stream>>>(Xb, T1b, T2b, Wf, b1, b2, b3, out);
}

// Round 5
// 572.207 us; speedup vs baseline: 1.2764x; 1.2744x over previous
//
#include <hip/hip_runtime.h>
#include <hip/hip_bf16.h>
#include <stdint.h>

#define NN    100000
#define NROWP 100096   // padded rows (gemm tail reads up to 100031)
#define NE    1600000
#define FIN   128
#define FOUT  200
#define NBLK  391      // ceil(NN/256)

typedef __attribute__((ext_vector_type(8))) short short8;
typedef __attribute__((ext_vector_type(8))) unsigned short ushort8;
typedef __attribute__((ext_vector_type(4))) float f32x4;
typedef __attribute__((ext_vector_type(4))) unsigned int uint32x4;

__device__ __forceinline__ short f2bf(float f) {
    __hip_bfloat16 h = __float2bfloat16(f);
    return *reinterpret_cast<short*>(&h);
}
__device__ __forceinline__ unsigned short f2bfu(float f) {
    __hip_bfloat16 h = __float2bfloat16(f);
    return *reinterpret_cast<unsigned short*>(&h);
}
__device__ __forceinline__ float bf2f(unsigned short u) {
    return __uint_as_float((unsigned)u << 16);
}
__device__ __forceinline__ int getidx(const void* ei, int isI32, long long i) {
    return isI32 ? ((const int*)ei)[i] : (int)((const long long*)ei)[i];
}

// --- dtype detection: read edge_index as int64; if any value out of [0,NN), it is int32 ---
__global__ void detect_kernel(const long long* ei64, int* flag) {
    int t = blockIdx.x * blockDim.x + threadIdx.x;   // 4096 samples
    long long v = ei64[t];
    if (v < 0 || v >= NN) atomicOr(flag, 1);
}

__global__ void x2bf_kernel(const float* __restrict__ x, unsigned short* __restrict__ xb) {
    long long i = ((long long)blockIdx.x * 256 + threadIdx.x) * 8;   // NN*FIN exact
    f32x4 v0 = *(const f32x4*)(x + i);
    f32x4 v1 = *(const f32x4*)(x + i + 4);
    ushort8 o;
    #pragma unroll
    for (int k = 0; k < 4; ++k) { o[k] = f2bfu(v0[k]); o[4 + k] = f2bfu(v1[k]); }
    *(ushort8*)(xb + i) = o;
}

// deg[r] += w ; cnt[r] += 1   (fused)
__global__ void deg_count_kernel(const void* ei, const int* flag, const float* w,
                                 float* deg, int* cnt) {
    int e = blockIdx.x * blockDim.x + threadIdx.x;   // NE exact
    int r = getidx(ei, *flag, e);
    atomicAdd(&deg[r], w[e]);
    atomicAdd(&cnt[r], 1);
}

// hierarchical exclusive scan of cnt -> rowstart
__global__ void scan_block(const int* __restrict__ cnt, int* __restrict__ rowstart,
                           int* __restrict__ bsum) {
    __shared__ int tmp[256];
    int i = blockIdx.x * 256 + threadIdx.x;
    int v = (i < NN) ? cnt[i] : 0;
    tmp[threadIdx.x] = v;
    __syncthreads();
    for (int off = 1; off < 256; off <<= 1) {
        int t = (threadIdx.x >= off) ? tmp[threadIdx.x - off] : 0;
        __syncthreads();
        tmp[threadIdx.x] += t;
        __syncthreads();
    }
    if (i < NN) rowstart[i] = tmp[threadIdx.x] - v;
    if (threadIdx.x == 255) bsum[blockIdx.x] = tmp[255];
}

__global__ void scan_bsums(int* bsum) {   // 1 block, 512 threads
    __shared__ int tmp[512];
    int t = threadIdx.x;
    int v = (t < NBLK) ? bsum[t] : 0;
    tmp[t] = v;
    __syncthreads();
    for (int off = 1; off < 512; off <<= 1) {
        int u = (t >= off) ? tmp[t - off] : 0;
        __syncthreads();
        tmp[t] += u;
        __syncthreads();
    }
    if (t < NBLK) bsum[t] = tmp[t] - v;
}

__global__ void scan_add(int* __restrict__ rowstart, const int* __restrict__ bsum,
                         int* __restrict__ cnt) {
    int i = blockIdx.x * 256 + threadIdx.x;
    if (i < NN) {
        rowstart[i] += bsum[i >> 8];
        cnt[i] = 0;                 // reuse cnt as fill counter
    } else if (i == NN) {
        rowstart[NN] = NE;
    }
}

// counting-sort edges by destination row; edge record = {col, norm_bits}
__global__ void fill_csr(const void* ei, const int* flag, const float* __restrict__ w,
                         const float* __restrict__ deg, const int* __restrict__ rowstart,
                         int* __restrict__ fill, int2* __restrict__ edge) {
    int e = blockIdx.x * blockDim.x + threadIdx.x;   // NE exact
    int isI32 = *flag;
    int r = getidx(ei, isI32, e);
    int c = getidx(ei, isI32, (long long)NE + e);
    float dr = deg[r], dc = deg[c];
    float ir = dr > 0.f ? rsqrtf(dr) : 0.f;
    float ic = dc > 0.f ? rsqrtf(dc) : 0.f;
    int pos = rowstart[r] + atomicAdd(&fill[r], 1);
    int2 rec; rec.x = c; rec.y = __float_as_int(-w[e] * ir * ic);
    edge[pos] = rec;
}

// one wave per destination row, quarter-wave per edge, bf16 rows (256B).
// MODE 0: dst = P(src); MODE 1: dst = 2*P(src) - x
template <int MODE>
__launch_bounds__(256)
__global__ void gather_prop(const int* __restrict__ rowstart, const int2* __restrict__ edge,
                            const unsigned short* __restrict__ srcb,
                            const unsigned short* __restrict__ xb,
                            unsigned short* __restrict__ dstb) {
    int gw   = (blockIdx.x << 2) + (threadIdx.x >> 6);   // row
    int lane = threadIdx.x & 63;
    int q = lane >> 4, fl = lane & 15;                   // quarter, 16B chunk
    int s = rowstart[gw], eend = rowstart[gw + 1];
    float a[8] = {0.f,0.f,0.f,0.f,0.f,0.f,0.f,0.f};
    for (int e = s + q; e < eend; e += 4) {
        int2 ed = edge[e];
        float w = __int_as_float(ed.y);
        ushort8 v = *(const ushort8*)(srcb + ((long long)ed.x << 7) + (fl << 3));
        #pragma unroll
        for (int i = 0; i < 8; ++i) a[i] += w * bf2f(v[i]);
    }
    #pragma unroll
    for (int i = 0; i < 8; ++i) {
        a[i] += __shfl_xor(a[i], 16);
        a[i] += __shfl_xor(a[i], 32);
    }
    if (lane < 16) {
        ushort8 o;
        if (MODE == 1) {
            ushort8 xv = *(const ushort8*)(xb + ((long long)gw << 7) + (fl << 3));
            #pragma unroll
            for (int i = 0; i < 8; ++i) o[i] = f2bfu(2.f * a[i] - bf2f(xv[i]));
        } else {
            #pragma unroll
            for (int i = 0; i < 8; ++i) o[i] = f2bfu(a[i]);
        }
        *(ushort8*)(dstb + ((long long)gw << 7) + (fl << 3)) = o;
    }
}

// ---------------------------------------------------------------------------
// Weight prep: pack W into MFMA B-fragment order.
// Frag unit (tile t, kstep ks) of scale s at unit index fb(s) + t*nk + ks,
// nk = 4(s+1), fb = {0, 52, 156}.  Lane l holds W_s[k=ks*32+(l>>4)*8+i][col=t*16+(l&15)].
// ---------------------------------------------------------------------------
__global__ void wprep_frag(const float* __restrict__ W1, const float* __restrict__ W2,
                           const float* __restrict__ W3, short* __restrict__ Wf) {
    __shared__ float lds[32 * 200];
    int bid = blockIdx.x;
    int s, ks;
    if (bid < 4)       { s = 0; ks = bid; }
    else if (bid < 12) { s = 1; ks = bid - 4; }
    else               { s = 2; ks = bid - 12; }
    const float* W = (s == 0) ? W1 : ((s == 1) ? W2 : W3);
    int p = ks >> 2;
    const float* Wp = W + (p * 128 + (ks & 3) * 32) * 200;
    for (int e = threadIdx.x; e < 6400; e += 256) lds[e] = Wp[e];
    __syncthreads();
    int nk = (s + 1) * 4;
    int fb = (s == 0) ? 0 : ((s == 1) ? 52 : 156);
    for (int qq = threadIdx.x; qq < 13 * 64; qq += 256) {
        int t = qq >> 6, lane = qq & 63;
        int col = t * 16 + (lane & 15);
        int kb  = (lane >> 4) * 8;
        short8 v;
        #pragma unroll
        for (int i = 0; i < 8; ++i) {
            float f = (col < FOUT) ? lds[(kb + i) * 200 + col] : 0.f;
            v[i] = f2bf(f);
        }
        *(short8*)&Wf[(fb + t * nk + ks) * 512 + lane * 8] = v;
    }
}

// ---------------------------------------------------------------------------
// Fused GEMM: 512 threads = 8 waves, BM=64 rows, all 3 scales in one pass.
// 39 (scale,tile) units statically partitioned across waves (balanced by
// k-step weight 4(sc+1)); each wave: acc[5 units][4 row-frags] = 80 VGPR.
// Stage 3 panels (48KB, XOR-swizzled 16B chunks) once, ONE barrier, then
// per (p,k4): 4 ds_read_b128 A-frags + per-unit 1KB B-frag (L2-hot) + 4 MFMA.
// ---------------------------------------------------------------------------
__constant__ int u_sc[8][5] = {
    {2,2,1,0,0}, {2,2,1,0,0}, {2,2,1,0,0}, {2,2,1,0,0},
    {2,2,1,0,0}, {2,2,1,0,0}, {2,1,1,1,0}, {1,1,1,1,-1}};
__constant__ int u_t[8][5] = {
    {0,1,0,0,1},     {2,3,1,2,3},    {4,5,2,4,5},    {6,7,3,6,7},
    {8,9,4,8,9},     {10,11,5,10,11},{12,6,7,8,12},  {9,10,11,12,0}};

__launch_bounds__(512, 2)
__global__ void gemm_fused(const unsigned short* __restrict__ xb,
                           const unsigned short* __restrict__ t1b,
                           const unsigned short* __restrict__ t2b,
                           const short* __restrict__ Wf,
                           const float* __restrict__ b1, const float* __restrict__ b2,
                           const float* __restrict__ b3, float* __restrict__ out) {
    __shared__ __align__(16) short As[3 * 64 * 128];   // 48 KB
    const int tid  = threadIdx.x;
    const int wave = tid >> 6;
    const int lane = tid & 63;
    const int l15  = lane & 15;
    const int lhi  = lane >> 4;
    const int b0   = blockIdx.x * 64;

    const unsigned short* panels[3] = {xb, t1b, t2b};
    // stage: 3072 chunks of 16B, 6 per thread, coalesced reads, swizzled writes
    #pragma unroll
    for (int i = 0; i < 6; ++i) {
        int q   = i * 512 + tid;
        int p   = q >> 10;
        int rem = q & 1023;
        int row = rem >> 4;
        int ch  = rem & 15;
        uint32x4 v = *(const uint32x4*)(panels[p] + ((long long)(b0 + row) << 7) + (ch << 3));
        *(uint32x4*)&As[((p * 64 + row) * 16 + (ch ^ (row & 7))) * 8] = v;
    }
    __syncthreads();

    int usc[5], ubase[5], ucol0[5];
    #pragma unroll
    for (int j = 0; j < 5; ++j) {
        int sc = u_sc[wave][j], t = u_t[wave][j];
        usc[j]   = sc;
        ucol0[j] = t * 16;
        int nk = 4 * (sc + 1);
        int fb = (sc == 0) ? 0 : ((sc == 1) ? 52 : 156);
        ubase[j] = fb + t * nk;
    }

    f32x4 acc[5][4];
    #pragma unroll
    for (int j = 0; j < 5; ++j)
        #pragma unroll
        for (int m = 0; m < 4; ++m) acc[j][m] = {0.f, 0.f, 0.f, 0.f};

    #pragma unroll 1
    for (int p = 0; p < 3; ++p) {
        #pragma unroll
        for (int k4 = 0; k4 < 4; ++k4) {
            short8 af[4];
            #pragma unroll
            for (int m = 0; m < 4; ++m) {
                int row = m * 16 + l15;
                int ch  = (k4 * 4 + lhi) ^ (row & 7);
                af[m] = *(const short8*)&As[((p * 64 + row) * 16 + ch) * 8];
            }
            #pragma unroll
            for (int j = 0; j < 5; ++j) {
                if (usc[j] >= p) {   // -1 sentinel never passes
                    const short* bp = Wf + (long long)(ubase[j] + p * 4 + k4) * 512 + lane * 8;
                    short8 bf = *(const short8*)bp;
                    #pragma unroll
                    for (int m = 0; m < 4; ++m)
                        acc[j][m] = __builtin_amdgcn_mfma_f32_16x16x32_bf16(af[m], bf, acc[j][m], 0, 0, 0);
                }
            }
        }
    }

    #pragma unroll
    for (int j = 0; j < 5; ++j) {
        if (usc[j] >= 0) {
            int col = ucol0[j] + l15;
            if (col < FOUT) {
                const float* bias = (usc[j] == 0) ? b1 : ((usc[j] == 1) ? b2 : b3);
                float bv = bias[col];
                float* op = out + (long long)usc[j] * NN * FOUT;
                #pragma unroll
                for (int m = 0; m < 4; ++m) {
                    int rb = b0 + m * 16 + lhi * 4;
                    #pragma unroll
                    for (int jj = 0; jj < 4; ++jj) {
                        int r = rb + jj;
                        if (r < NN) op[(long long)r * FOUT + col] = acc[j][m][jj] + bv;
                    }
                }
            }
        }
    }
}

extern "C" void kernel_launch(void* const* d_in, const int* in_sizes, int n_in,
                              void* d_out, int out_size, void* d_ws, size_t ws_size,
                              hipStream_t stream) {
    const float* x  = (const float*)d_in[0];
    const void*  ei = d_in[1];
    const float* ew = (const float*)d_in[2];
    const float* W1 = (const float*)d_in[3];
    const float* b1 = (const float*)d_in[4];
    const float* W2 = (const float*)d_in[5];
    const float* b2 = (const float*)d_in[6];
    const float* W3 = (const float*)d_in[7];
    const float* b3 = (const float*)d_in[8];
    float* out = (float*)d_out;

    char* ws = (char*)d_ws;
    // layout (bytes):
    // [0,16)                 flag        } zeroed
    // [16, 400016)           deg  N f32  } zeroed
    // [400016, 800016)       cnt  N i32  } zeroed
    // [800016, 1200020)      rowstart N+1
    // [1200032, 1202080)     bsum 512
    // [1202080, 14002080)    edge int2 E
    // [14002080, 39626656)   Xb  bf16 NROWP*128
    // [39626656, 65251232)   T1b bf16
    // [65251232, 90875808)   T2b bf16
    // [90875808, 91195296)   Wf  bf16 frags (312 KB)
    int*   flag     = (int*)(ws + 0);
    float* deg      = (float*)(ws + 16);
    int*   cnt      = (int*)(ws + 400016);
    int*   rowstart = (int*)(ws + 800016);
    int*   bsum     = (int*)(ws + 1200032);
    int2*  edge     = (int2*)(ws + 1202080);
    unsigned short* Xb  = (unsigned short*)(ws + 14002080);
    unsigned short* T1b = (unsigned short*)(ws + 39626656);
    unsigned short* T2b = (unsigned short*)(ws + 65251232);
    short* Wf       = (short*)(ws + 90875808);

    hipMemsetAsync(d_ws, 0, 800016, stream);   // flag + deg + cnt

    detect_kernel<<<16, 256, 0, stream>>>((const long long*)ei, flag);
    x2bf_kernel<<<6250, 256, 0, stream>>>(x, Xb);
    deg_count_kernel<<<NE / 256, 256, 0, stream>>>(ei, flag, ew, deg, cnt);
    scan_block<<<NBLK, 256, 0, stream>>>(cnt, rowstart, bsum);
    scan_bsums<<<1, 512, 0, stream>>>(bsum);
    scan_add<<<NBLK + 1, 256, 0, stream>>>(rowstart, bsum, cnt);
    fill_csr<<<NE / 256, 256, 0, stream>>>(ei, flag, ew, deg, rowstart, cnt, edge);
    gather_prop<0><<<NN / 4, 256, 0, stream>>>(rowstart, edge, Xb, nullptr, T1b);
    gather_prop<1><<<NN / 4, 256, 0, stream>>>(rowstart, edge, T1b, Xb, T2b);
    wprep_frag<<<24, 256, 0, stream>>>(W1, W2, W3, Wf);
    gemm_fused<<<1563, 512, 0, stream>>>(Xb, T1b, T2b, Wf, b1, b2, b3, out);
}

// Round 6
// 529.982 us; speedup vs baseline: 1.3781x; 1.0797x over previous
//
#include <hip/hip_runtime.h>
#include <hip/hip_bf16.h>
#include <stdint.h>

#define NN    100000
#define NROWP 100096   // padded rows (gemm tail reads up to 100031)
#define NE    1600000
#define FIN   128
#define FOUT  200
#define NBLK  391      // ceil(NN/256)

typedef __attribute__((ext_vector_type(8))) short short8;
typedef __attribute__((ext_vector_type(8))) unsigned short ushort8;
typedef __attribute__((ext_vector_type(4))) float f32x4;
typedef __attribute__((ext_vector_type(4))) unsigned int uint32x4;

__device__ __forceinline__ short f2bf(float f) {
    __hip_bfloat16 h = __float2bfloat16(f);
    return *reinterpret_cast<short*>(&h);
}
__device__ __forceinline__ unsigned short f2bfu(float f) {
    __hip_bfloat16 h = __float2bfloat16(f);
    return *reinterpret_cast<unsigned short*>(&h);
}
__device__ __forceinline__ float bf2f(unsigned short u) {
    return __uint_as_float((unsigned)u << 16);
}
__device__ __forceinline__ int getidx(const void* ei, int isI32, long long i) {
    return isI32 ? ((const int*)ei)[i] : (int)((const long long*)ei)[i];
}

// --- dtype detection: read edge_index as int64; if any value out of [0,NN), it is int32 ---
__global__ void detect_kernel(const long long* ei64, int* flag) {
    int t = blockIdx.x * blockDim.x + threadIdx.x;   // 4096 samples
    long long v = ei64[t];
    if (v < 0 || v >= NN) atomicOr(flag, 1);
}

__global__ void x2bf_kernel(const float* __restrict__ x, unsigned short* __restrict__ xb) {
    long long i = ((long long)blockIdx.x * 256 + threadIdx.x) * 8;   // NN*FIN exact
    f32x4 v0 = *(const f32x4*)(x + i);
    f32x4 v1 = *(const f32x4*)(x + i + 4);
    ushort8 o;
    #pragma unroll
    for (int k = 0; k < 4; ++k) { o[k] = f2bfu(v0[k]); o[4 + k] = f2bfu(v1[k]); }
    *(ushort8*)(xb + i) = o;
}

// deg[r] += w ; cnt[r] += 1   (fused)
__global__ void deg_count_kernel(const void* ei, const int* flag, const float* w,
                                 float* deg, int* cnt) {
    int e = blockIdx.x * blockDim.x + threadIdx.x;   // NE exact
    int r = getidx(ei, *flag, e);
    atomicAdd(&deg[r], w[e]);
    atomicAdd(&cnt[r], 1);
}

// hierarchical exclusive scan of cnt -> rowstart
__global__ void scan_block(const int* __restrict__ cnt, int* __restrict__ rowstart,
                           int* __restrict__ bsum) {
    __shared__ int tmp[256];
    int i = blockIdx.x * 256 + threadIdx.x;
    int v = (i < NN) ? cnt[i] : 0;
    tmp[threadIdx.x] = v;
    __syncthreads();
    for (int off = 1; off < 256; off <<= 1) {
        int t = (threadIdx.x >= off) ? tmp[threadIdx.x - off] : 0;
        __syncthreads();
        tmp[threadIdx.x] += t;
        __syncthreads();
    }
    if (i < NN) rowstart[i] = tmp[threadIdx.x] - v;
    if (threadIdx.x == 255) bsum[blockIdx.x] = tmp[255];
}

__global__ void scan_bsums(int* bsum) {   // 1 block, 512 threads
    __shared__ int tmp[512];
    int t = threadIdx.x;
    int v = (t < NBLK) ? bsum[t] : 0;
    tmp[t] = v;
    __syncthreads();
    for (int off = 1; off < 512; off <<= 1) {
        int u = (t >= off) ? tmp[t - off] : 0;
        __syncthreads();
        tmp[t] += u;
        __syncthreads();
    }
    if (t < NBLK) bsum[t] = tmp[t] - v;
}

__global__ void scan_add(int* __restrict__ rowstart, const int* __restrict__ bsum,
                         int* __restrict__ cnt) {
    int i = blockIdx.x * 256 + threadIdx.x;
    if (i < NN) {
        rowstart[i] += bsum[i >> 8];
        cnt[i] = 0;                 // reuse cnt as fill counter
    } else if (i == NN) {
        rowstart[NN] = NE;
    }
}

// counting-sort edges by destination row; edge record = {col, norm_bits}
__global__ void fill_csr(const void* ei, const int* flag, const float* __restrict__ w,
                         const float* __restrict__ deg, const int* __restrict__ rowstart,
                         int* __restrict__ fill, int2* __restrict__ edge) {
    int e = blockIdx.x * blockDim.x + threadIdx.x;   // NE exact
    int isI32 = *flag;
    int r = getidx(ei, isI32, e);
    int c = getidx(ei, isI32, (long long)NE + e);
    float dr = deg[r], dc = deg[c];
    float ir = dr > 0.f ? rsqrtf(dr) : 0.f;
    float ic = dc > 0.f ? rsqrtf(dc) : 0.f;
    int pos = rowstart[r] + atomicAdd(&fill[r], 1);
    int2 rec; rec.x = c; rec.y = __float_as_int(-w[e] * ir * ic);
    edge[pos] = rec;
}

// one wave per destination row, quarter-wave per edge, 2 edges in flight per
// quarter (dual accumulators). bf16 rows (256B).
// MODE 0: dst = P(src); MODE 1: dst = 2*P(src) - x
template <int MODE>
__launch_bounds__(256)
__global__ void gather_prop(const int* __restrict__ rowstart, const int2* __restrict__ edge,
                            const unsigned short* __restrict__ srcb,
                            const unsigned short* __restrict__ xb,
                            unsigned short* __restrict__ dstb) {
    int gw   = (blockIdx.x << 2) + (threadIdx.x >> 6);   // row
    int lane = threadIdx.x & 63;
    int q = lane >> 4, fl = lane & 15;                   // quarter, 16B chunk
    int s = rowstart[gw], eend = rowstart[gw + 1];
    float a0[8] = {0.f,0.f,0.f,0.f,0.f,0.f,0.f,0.f};
    float a1[8] = {0.f,0.f,0.f,0.f,0.f,0.f,0.f,0.f};
    int e = s + q;
    for (; e + 4 < eend; e += 8) {
        int2 ed0 = edge[e];
        int2 ed1 = edge[e + 4];
        ushort8 v0 = *(const ushort8*)(srcb + ((long long)ed0.x << 7) + (fl << 3));
        ushort8 v1 = *(const ushort8*)(srcb + ((long long)ed1.x << 7) + (fl << 3));
        float w0 = __int_as_float(ed0.y);
        float w1 = __int_as_float(ed1.y);
        #pragma unroll
        for (int i = 0; i < 8; ++i) {
            a0[i] += w0 * bf2f(v0[i]);
            a1[i] += w1 * bf2f(v1[i]);
        }
    }
    if (e < eend) {
        int2 ed = edge[e];
        float w = __int_as_float(ed.y);
        ushort8 v = *(const ushort8*)(srcb + ((long long)ed.x << 7) + (fl << 3));
        #pragma unroll
        for (int i = 0; i < 8; ++i) a0[i] += w * bf2f(v[i]);
    }
    #pragma unroll
    for (int i = 0; i < 8; ++i) {
        a0[i] += a1[i];
        a0[i] += __shfl_xor(a0[i], 16);
        a0[i] += __shfl_xor(a0[i], 32);
    }
    if (lane < 16) {
        ushort8 o;
        if (MODE == 1) {
            ushort8 xv = *(const ushort8*)(xb + ((long long)gw << 7) + (fl << 3));
            #pragma unroll
            for (int i = 0; i < 8; ++i) o[i] = f2bfu(2.f * a0[i] - bf2f(xv[i]));
        } else {
            #pragma unroll
            for (int i = 0; i < 8; ++i) o[i] = f2bfu(a0[i]);
        }
        *(ushort8*)(dstb + ((long long)gw << 7) + (fl << 3)) = o;
    }
}

// ---------------------------------------------------------------------------
// Weight prep: pack W into MFMA B-fragment order.
// Frag unit (tile t, kstep ks) of scale s at unit index fb(s) + t*nk + ks,
// nk = 4(s+1), fb = {0, 52, 156}.  Lane l holds W_s[k=ks*32+(l>>4)*8+i][col=t*16+(l&15)].
// ---------------------------------------------------------------------------
__global__ void wprep_frag(const float* __restrict__ W1, const float* __restrict__ W2,
                           const float* __restrict__ W3, short* __restrict__ Wf) {
    __shared__ float lds[32 * 200];
    int bid = blockIdx.x;
    int s, ks;
    if (bid < 4)       { s = 0; ks = bid; }
    else if (bid < 12) { s = 1; ks = bid - 4; }
    else               { s = 2; ks = bid - 12; }
    const float* W = (s == 0) ? W1 : ((s == 1) ? W2 : W3);
    int p = ks >> 2;
    const float* Wp = W + (p * 128 + (ks & 3) * 32) * 200;
    for (int e = threadIdx.x; e < 6400; e += 256) lds[e] = Wp[e];
    __syncthreads();
    int nk = (s + 1) * 4;
    int fb = (s == 0) ? 0 : ((s == 1) ? 52 : 156);
    for (int qq = threadIdx.x; qq < 13 * 64; qq += 256) {
        int t = qq >> 6, lane = qq & 63;
        int col = t * 16 + (lane & 15);
        int kb  = (lane >> 4) * 8;
        short8 v;
        #pragma unroll
        for (int i = 0; i < 8; ++i) {
            float f = (col < FOUT) ? lds[(kb + i) * 200 + col] : 0.f;
            v[i] = f2bf(f);
        }
        *(short8*)&Wf[(fb + t * nk + ks) * 512 + lane * 8] = v;
    }
}

// ---------------------------------------------------------------------------
// Fused GEMM: 512 threads = 8 waves, BM=64 rows, all 3 scales in one pass.
// 39 (scale,tile) units statically partitioned across waves; acc[5][4]=80.
// B-frags double-buffered in registers (load step+1 during step's MFMAs).
// Epilogue: per scale, deposit acc to LDS f32 [64][212] then store full rows
// coalesced (exact 240MB writes).
// ---------------------------------------------------------------------------
__constant__ int u_sc[8][5] = {
    {2,2,1,0,0}, {2,2,1,0,0}, {2,2,1,0,0}, {2,2,1,0,0},
    {2,2,1,0,0}, {2,2,1,0,0}, {2,1,1,1,0}, {1,1,1,1,-1}};
__constant__ int u_t[8][5] = {
    {0,1,0,0,1},     {2,3,1,2,3},    {4,5,2,4,5},    {6,7,3,6,7},
    {8,9,4,8,9},     {10,11,5,10,11},{12,6,7,8,12},  {9,10,11,12,0}};

#define EPAD 212   // f32 row stride in epilogue LDS (4-row stride = 16 banks)

__launch_bounds__(512, 2)
__global__ void gemm_fused(const unsigned short* __restrict__ xb,
                           const unsigned short* __restrict__ t1b,
                           const unsigned short* __restrict__ t2b,
                           const short* __restrict__ Wf,
                           const float* __restrict__ b1, const float* __restrict__ b2,
                           const float* __restrict__ b3, float* __restrict__ out) {
    __shared__ __align__(16) char smem[64 * EPAD * 4];   // 54272B >= 49152B As
    short* As = (short*)smem;                             // [3][64][16 chunks][8]
    float* Ef = (float*)smem;                             // [64][EPAD]

    const int tid  = threadIdx.x;
    const int wave = tid >> 6;
    const int lane = tid & 63;
    const int l15  = lane & 15;
    const int lhi  = lane >> 4;
    const int b0   = blockIdx.x * 64;

    const unsigned short* panels[3] = {xb, t1b, t2b};
    // stage: 3072 chunks of 16B, 6 per thread, coalesced reads, swizzled writes
    #pragma unroll
    for (int i = 0; i < 6; ++i) {
        int q   = i * 512 + tid;
        int p   = q >> 10;
        int rem = q & 1023;
        int row = rem >> 4;
        int ch  = rem & 15;
        uint32x4 v = *(const uint32x4*)(panels[p] + ((long long)(b0 + row) << 7) + (ch << 3));
        *(uint32x4*)&As[((p * 64 + row) * 16 + (ch ^ (row & 7))) * 8] = v;
    }

    int usc[5], ubase[5], ucol0[5];
    #pragma unroll
    for (int j = 0; j < 5; ++j) {
        int sc = u_sc[wave][j], t = u_t[wave][j];
        usc[j]   = sc;
        ucol0[j] = t * 16;
        int nk = 4 * (sc + 1);
        int fb = (sc == 0) ? 0 : ((sc == 1) ? 52 : 156);
        ubase[j] = fb + t * nk;
    }

    f32x4 acc[5][4];
    #pragma unroll
    for (int j = 0; j < 5; ++j)
        #pragma unroll
        for (int m = 0; m < 4; ++m) acc[j][m] = {0.f, 0.f, 0.f, 0.f};

    short8 bf[2][5];
    #pragma unroll
    for (int j = 0; j < 5; ++j)
        bf[0][j] = *(const short8*)(Wf + (long long)(ubase[j] + 0) * 512 + lane * 8);

    __syncthreads();

    #pragma unroll
    for (int step = 0; step < 12; ++step) {
        const int p   = step >> 2;
        const int k4  = step & 3;
        const int cur = step & 1;
        if (step < 11) {
            #pragma unroll
            for (int j = 0; j < 5; ++j)
                bf[cur ^ 1][j] = *(const short8*)(Wf + (long long)(ubase[j] + step + 1) * 512 + lane * 8);
        }
        short8 af[4];
        #pragma unroll
        for (int m = 0; m < 4; ++m) {
            int row = m * 16 + l15;
            int ch  = (k4 * 4 + lhi) ^ (row & 7);
            af[m] = *(const short8*)&As[((p * 64 + row) * 16 + ch) * 8];
        }
        #pragma unroll
        for (int j = 0; j < 5; ++j) {
            if (usc[j] >= p) {   // wave-uniform (scalar) branch; -1 sentinel never passes
                #pragma unroll
                for (int m = 0; m < 4; ++m)
                    acc[j][m] = __builtin_amdgcn_mfma_f32_16x16x32_bf16(af[m], bf[cur][j], acc[j][m], 0, 0, 0);
            }
        }
    }

    // epilogue: per scale, deposit to LDS then store coalesced full rows
    #pragma unroll 1
    for (int sc = 0; sc < 3; ++sc) {
        __syncthreads();
        const float* bias = (sc == 0) ? b1 : ((sc == 1) ? b2 : b3);
        #pragma unroll
        for (int j = 0; j < 5; ++j) {
            if (usc[j] == sc) {
                int col = ucol0[j] + l15;
                if (col < FOUT) {
                    float bv = bias[col];
                    #pragma unroll
                    for (int m = 0; m < 4; ++m) {
                        int rbase = m * 16 + lhi * 4;
                        #pragma unroll
                        for (int jj = 0; jj < 4; ++jj)
                            Ef[(rbase + jj) * EPAD + col] = acc[j][m][jj] + bv;
                    }
                }
            }
        }
        __syncthreads();
        float* op = out + (long long)sc * NN * FOUT;
        for (int c = tid; c < 3200; c += 512) {   // 64 rows x 50 f32x4 chunks
            int r = c / 50, pos = c % 50;
            int row = b0 + r;
            if (row < NN) {
                f32x4 v = *(const f32x4*)&Ef[r * EPAD + pos * 4];
                *(f32x4*)&op[(long long)row * FOUT + pos * 4] = v;
            }
        }
    }
}

extern "C" void kernel_launch(void* const* d_in, const int* in_sizes, int n_in,
                              void* d_out, int out_size, void* d_ws, size_t ws_size,
                              hipStream_t stream) {
    const float* x  = (const float*)d_in[0];
    const void*  ei = d_in[1];
    const float* ew = (const float*)d_in[2];
    const float* W1 = (const float*)d_in[3];
    const float* b1 = (const float*)d_in[4];
    const float* W2 = (const float*)d_in[5];
    const float* b2 = (const float*)d_in[6];
    const float* W3 = (const float*)d_in[7];
    const float* b3 = (const float*)d_in[8];
    float* out = (float*)d_out;

    char* ws = (char*)d_ws;
    // layout (bytes):
    // [0,16)                 flag        } zeroed
    // [16, 400016)           deg  N f32  } zeroed
    // [400016, 800016)       cnt  N i32  } zeroed
    // [800016, 1200020)      rowstart N+1
    // [1200032, 1202080)     bsum 512
    // [1202080, 14002080)    edge int2 E
    // [14002080, 39626656)   Xb  bf16 NROWP*128
    // [39626656, 65251232)   T1b bf16
    // [65251232, 90875808)   T2b bf16
    // [90875808, 91195296)   Wf  bf16 frags (312 KB)
    int*   flag     = (int*)(ws + 0);
    float* deg      = (float*)(ws + 16);
    int*   cnt      = (int*)(ws + 400016);
    int*   rowstart = (int*)(ws + 800016);
    int*   bsum     = (int*)(ws + 1200032);
    int2*  edge     = (int2*)(ws + 1202080);
    unsigned short* Xb  = (unsigned short*)(ws + 14002080);
    unsigned short* T1b = (unsigned short*)(ws + 39626656);
    unsigned short* T2b = (unsigned short*)(ws + 65251232);
    short* Wf       = (short*)(ws + 90875808);

    hipMemsetAsync(d_ws, 0, 800016, stream);   // flag + deg + cnt

    detect_kernel<<<16, 256, 0, stream>>>((const long long*)ei, flag);
    x2bf_kernel<<<6250, 256, 0, stream>>>(x, Xb);
    deg_count_kernel<<<NE / 256, 256, 0, stream>>>(ei, flag, ew, deg, cnt);
    scan_block<<<NBLK, 256, 0, stream>>>(cnt, rowstart, bsum);
    scan_bsums<<<1, 512, 0, stream>>>(bsum);
    scan_add<<<NBLK + 1, 256, 0, stream>>>(rowstart, bsum, cnt);
    fill_csr<<<NE / 256, 256, 0, stream>>>(ei, flag, ew, deg, rowstart, cnt, edge);
    gather_prop<0><<<NN / 4, 256, 0, stream>>>(rowstart, edge, Xb, nullptr, T1b);
    gather_prop<1><<<NN / 4, 256, 0, stream>>>(rowstart, edge, T1b, Xb, T2b);
    wprep_frag<<<24, 256, 0, stream>>>(W1, W2, W3, Wf);
    gemm_fused<<<1563, 512, 0, stream>>>(Xb, T1b, T2b, Wf, b1, b2, b3, out);
}

// Round 7
// 473.758 us; speedup vs baseline: 1.5417x; 1.1187x over previous
//
#include <hip/hip_runtime.h>
#include <hip/hip_bf16.h>
#include <stdint.h>

#define NN    100000
#define NROWP 100096   // padded rows (gemm tail reads up to 100031)
#define NE    1600000
#define FIN   128
#define FOUT  200
#define NBLK  391      // ceil(NN/256)

typedef __attribute__((ext_vector_type(8))) short short8;
typedef __attribute__((ext_vector_type(8))) unsigned short ushort8;
typedef __attribute__((ext_vector_type(4))) float f32x4;
typedef __attribute__((ext_vector_type(4))) unsigned int uint32x4;

__device__ __forceinline__ short f2bf(float f) {
    __hip_bfloat16 h = __float2bfloat16(f);
    return *reinterpret_cast<short*>(&h);
}
__device__ __forceinline__ unsigned short f2bfu(float f) {
    __hip_bfloat16 h = __float2bfloat16(f);
    return *reinterpret_cast<unsigned short*>(&h);
}
__device__ __forceinline__ float bf2f(unsigned short u) {
    return __uint_as_float((unsigned)u << 16);
}
__device__ __forceinline__ int getidx(const void* ei, int isI32, long long i) {
    return isI32 ? ((const int*)ei)[i] : (int)((const long long*)ei)[i];
}

// --- dtype detection: read edge_index as int64; if any value out of [0,NN), it is int32 ---
__global__ void detect_kernel(const long long* ei64, int* flag) {
    int t = blockIdx.x * blockDim.x + threadIdx.x;   // 4096 samples
    long long v = ei64[t];
    if (v < 0 || v >= NN) atomicOr(flag, 1);
}

__global__ void x2bf_kernel(const float* __restrict__ x, unsigned short* __restrict__ xb) {
    long long i = ((long long)blockIdx.x * 256 + threadIdx.x) * 8;   // NN*FIN exact
    f32x4 v0 = *(const f32x4*)(x + i);
    f32x4 v1 = *(const f32x4*)(x + i + 4);
    ushort8 o;
    #pragma unroll
    for (int k = 0; k < 4; ++k) { o[k] = f2bfu(v0[k]); o[4 + k] = f2bfu(v1[k]); }
    *(ushort8*)(xb + i) = o;
}

// per-replica histogram of destination rows; rep = blockIdx & 7 (XCD round-robin)
__global__ void cnt8_kernel(const void* ei, const int* flag, int* cnt8) {
    int e = blockIdx.x * blockDim.x + threadIdx.x;   // NE exact
    int r = getidx(ei, *flag, e);
    atomicAdd(&cnt8[(blockIdx.x & 7) * NN + r], 1);
}

// per-row: total count -> cnt; replace cnt8 slices with exclusive prefixes
__global__ void xreduce(int* __restrict__ cnt8, int* __restrict__ cnt) {
    int r = blockIdx.x * 256 + threadIdx.x;
    if (r >= NN) return;
    int s = 0;
    #pragma unroll
    for (int x = 0; x < 8; ++x) {
        int v = cnt8[x * NN + r];
        cnt8[x * NN + r] = s;
        s += v;
    }
    cnt[r] = s;
}

// hierarchical exclusive scan of cnt -> rowstart
__global__ void scan_block(const int* __restrict__ cnt, int* __restrict__ rowstart,
                           int* __restrict__ bsum) {
    __shared__ int tmp[256];
    int i = blockIdx.x * 256 + threadIdx.x;
    int v = (i < NN) ? cnt[i] : 0;
    tmp[threadIdx.x] = v;
    __syncthreads();
    for (int off = 1; off < 256; off <<= 1) {
        int t = (threadIdx.x >= off) ? tmp[threadIdx.x - off] : 0;
        __syncthreads();
        tmp[threadIdx.x] += t;
        __syncthreads();
    }
    if (i < NN) rowstart[i] = tmp[threadIdx.x] - v;
    if (threadIdx.x == 255) bsum[blockIdx.x] = tmp[255];
}

__global__ void scan_bsums(int* bsum) {   // 1 block, 512 threads
    __shared__ int tmp[512];
    int t = threadIdx.x;
    int v = (t < NBLK) ? bsum[t] : 0;
    tmp[t] = v;
    __syncthreads();
    for (int off = 1; off < 512; off <<= 1) {
        int u = (t >= off) ? tmp[t - off] : 0;
        __syncthreads();
        tmp[t] += u;
        __syncthreads();
    }
    if (t < NBLK) bsum[t] = tmp[t] - v;
}

__global__ void scan_add(int* __restrict__ rowstart, const int* __restrict__ bsum) {
    int i = blockIdx.x * 256 + threadIdx.x;
    if (i < NN)       rowstart[i] += bsum[i >> 8];
    else if (i == NN) rowstart[NN] = NE;
}

// counting-sort edges by destination row; rec = {col, w_bits}; position from
// rowstart + per-replica prefix + XCD-local atomic bump.
__global__ void fill_csr(const void* ei, const int* flag, const float* __restrict__ w,
                         const int* __restrict__ rowstart, int* __restrict__ cnt8,
                         int2* __restrict__ edge) {
    int e = blockIdx.x * blockDim.x + threadIdx.x;   // NE exact; SAME grid as cnt8_kernel
    int isI32 = *flag;
    int r = getidx(ei, isI32, e);
    int c = getidx(ei, isI32, (long long)NE + e);
    int pos = rowstart[r] + atomicAdd(&cnt8[(blockIdx.x & 7) * NN + r], 1);
    int2 rec; rec.x = c; rec.y = __float_as_int(w[e]);
    edge[pos] = rec;
}

// per-row segmented sum of sorted weights -> dis[r] = deg>0 ? rsqrt(deg) : 0
__global__ void deg_seg(const int* __restrict__ rowstart, const int2* __restrict__ edge,
                        float* __restrict__ dis) {
    int r = blockIdx.x * 256 + threadIdx.x;
    if (r >= NN) return;
    int s = rowstart[r], e = rowstart[r + 1];
    float d = 0.f;
    for (int i = s; i < e; ++i) d += __int_as_float(edge[i].y);
    dis[r] = d > 0.f ? rsqrtf(d) : 0.f;
}

// one wave per destination row, quarter-wave per edge, 2 edges in flight.
// norm computed on the fly: P[r] = -dis[r] * sum_e w_e*dis[c_e]*src[c_e].
// MODE 0: dst = P(src); MODE 1: dst = 2*P(src) - x
template <int MODE>
__launch_bounds__(256)
__global__ void gather_prop(const int* __restrict__ rowstart, const int2* __restrict__ edge,
                            const float* __restrict__ dis,
                            const unsigned short* __restrict__ srcb,
                            const unsigned short* __restrict__ xb,
                            unsigned short* __restrict__ dstb) {
    int gw   = (blockIdx.x << 2) + (threadIdx.x >> 6);   // row
    int lane = threadIdx.x & 63;
    int q = lane >> 4, fl = lane & 15;                   // quarter, 16B chunk
    int s = rowstart[gw], eend = rowstart[gw + 1];
    float a0[8] = {0.f,0.f,0.f,0.f,0.f,0.f,0.f,0.f};
    float a1[8] = {0.f,0.f,0.f,0.f,0.f,0.f,0.f,0.f};
    int e = s + q;
    for (; e + 4 < eend; e += 8) {
        int2 ed0 = edge[e];
        int2 ed1 = edge[e + 4];
        ushort8 v0 = *(const ushort8*)(srcb + ((long long)ed0.x << 7) + (fl << 3));
        ushort8 v1 = *(const ushort8*)(srcb + ((long long)ed1.x << 7) + (fl << 3));
        float w0 = __int_as_float(ed0.y) * dis[ed0.x];
        float w1 = __int_as_float(ed1.y) * dis[ed1.x];
        #pragma unroll
        for (int i = 0; i < 8; ++i) {
            a0[i] += w0 * bf2f(v0[i]);
            a1[i] += w1 * bf2f(v1[i]);
        }
    }
    if (e < eend) {
        int2 ed = edge[e];
        float w = __int_as_float(ed.y) * dis[ed.x];
        ushort8 v = *(const ushort8*)(srcb + ((long long)ed.x << 7) + (fl << 3));
        #pragma unroll
        for (int i = 0; i < 8; ++i) a0[i] += w * bf2f(v[i]);
    }
    #pragma unroll
    for (int i = 0; i < 8; ++i) {
        a0[i] += a1[i];
        a0[i] += __shfl_xor(a0[i], 16);
        a0[i] += __shfl_xor(a0[i], 32);
    }
    if (lane < 16) {
        float sr = -dis[gw];
        ushort8 o;
        if (MODE == 1) {
            ushort8 xv = *(const ushort8*)(xb + ((long long)gw << 7) + (fl << 3));
            #pragma unroll
            for (int i = 0; i < 8; ++i) o[i] = f2bfu(2.f * sr * a0[i] - bf2f(xv[i]));
        } else {
            #pragma unroll
            for (int i = 0; i < 8; ++i) o[i] = f2bfu(sr * a0[i]);
        }
        *(ushort8*)(dstb + ((long long)gw << 7) + (fl << 3)) = o;
    }
}

// ---------------------------------------------------------------------------
// Weight prep: pack W into MFMA B-fragment order.
// Frag unit (tile t, kstep ks) of scale s at unit index fb(s) + t*nk + ks,
// nk = 4(s+1), fb = {0, 52, 156}.  Lane l holds W_s[k=ks*32+(l>>4)*8+i][col=t*16+(l&15)].
// ---------------------------------------------------------------------------
__global__ void wprep_frag(const float* __restrict__ W1, const float* __restrict__ W2,
                           const float* __restrict__ W3, short* __restrict__ Wf) {
    __shared__ float lds[32 * 200];
    int bid = blockIdx.x;
    int s, ks;
    if (bid < 4)       { s = 0; ks = bid; }
    else if (bid < 12) { s = 1; ks = bid - 4; }
    else               { s = 2; ks = bid - 12; }
    const float* W = (s == 0) ? W1 : ((s == 1) ? W2 : W3);
    int p = ks >> 2;
    const float* Wp = W + (p * 128 + (ks & 3) * 32) * 200;
    for (int e = threadIdx.x; e < 6400; e += 256) lds[e] = Wp[e];
    __syncthreads();
    int nk = (s + 1) * 4;
    int fb = (s == 0) ? 0 : ((s == 1) ? 52 : 156);
    for (int qq = threadIdx.x; qq < 13 * 64; qq += 256) {
        int t = qq >> 6, lane = qq & 63;
        int col = t * 16 + (lane & 15);
        int kb  = (lane >> 4) * 8;
        short8 v;
        #pragma unroll
        for (int i = 0; i < 8; ++i) {
            float f = (col < FOUT) ? lds[(kb + i) * 200 + col] : 0.f;
            v[i] = f2bf(f);
        }
        *(short8*)&Wf[(fb + t * nk + ks) * 512 + lane * 8] = v;
    }
}

// ---------------------------------------------------------------------------
// Fused GEMM: 512 threads = 8 waves, BM=64 rows, all 3 scales in one pass.
// 39 (scale,tile) units statically partitioned across waves; acc[5][4]=80.
// B-frags double-buffered in registers; LDS-transpose epilogue for coalesced
// full-row stores.
// ---------------------------------------------------------------------------
__constant__ int u_sc[8][5] = {
    {2,2,1,0,0}, {2,2,1,0,0}, {2,2,1,0,0}, {2,2,1,0,0},
    {2,2,1,0,0}, {2,2,1,0,0}, {2,1,1,1,0}, {1,1,1,1,-1}};
__constant__ int u_t[8][5] = {
    {0,1,0,0,1},     {2,3,1,2,3},    {4,5,2,4,5},    {6,7,3,6,7},
    {8,9,4,8,9},     {10,11,5,10,11},{12,6,7,8,12},  {9,10,11,12,0}};

#define EPAD 212   // f32 row stride in epilogue LDS

__launch_bounds__(512, 2)
__global__ void gemm_fused(const unsigned short* __restrict__ xb,
                           const unsigned short* __restrict__ t1b,
                           const unsigned short* __restrict__ t2b,
                           const short* __restrict__ Wf,
                           const float* __restrict__ b1, const float* __restrict__ b2,
                           const float* __restrict__ b3, float* __restrict__ out) {
    __shared__ __align__(16) char smem[64 * EPAD * 4];   // 54272B >= 49152B As
    short* As = (short*)smem;                             // [3][64][16 chunks][8]
    float* Ef = (float*)smem;                             // [64][EPAD]

    const int tid  = threadIdx.x;
    const int wave = tid >> 6;
    const int lane = tid & 63;
    const int l15  = lane & 15;
    const int lhi  = lane >> 4;
    const int b0   = blockIdx.x * 64;

    const unsigned short* panels[3] = {xb, t1b, t2b};
    #pragma unroll
    for (int i = 0; i < 6; ++i) {
        int q   = i * 512 + tid;
        int p   = q >> 10;
        int rem = q & 1023;
        int row = rem >> 4;
        int ch  = rem & 15;
        uint32x4 v = *(const uint32x4*)(panels[p] + ((long long)(b0 + row) << 7) + (ch << 3));
        *(uint32x4*)&As[((p * 64 + row) * 16 + (ch ^ (row & 7))) * 8] = v;
    }

    int usc[5], ubase[5], ucol0[5];
    #pragma unroll
    for (int j = 0; j < 5; ++j) {
        int sc = u_sc[wave][j], t = u_t[wave][j];
        usc[j]   = sc;
        ucol0[j] = t * 16;
        int nk = 4 * (sc + 1);
        int fb = (sc == 0) ? 0 : ((sc == 1) ? 52 : 156);
        ubase[j] = fb + t * nk;
    }

    f32x4 acc[5][4];
    #pragma unroll
    for (int j = 0; j < 5; ++j)
        #pragma unroll
        for (int m = 0; m < 4; ++m) acc[j][m] = {0.f, 0.f, 0.f, 0.f};

    short8 bf[2][5];
    #pragma unroll
    for (int j = 0; j < 5; ++j)
        bf[0][j] = *(const short8*)(Wf + (long long)(ubase[j] + 0) * 512 + lane * 8);

    __syncthreads();

    #pragma unroll
    for (int step = 0; step < 12; ++step) {
        const int p   = step >> 2;
        const int k4  = step & 3;
        const int cur = step & 1;
        if (step < 11) {
            #pragma unroll
            for (int j = 0; j < 5; ++j)
                bf[cur ^ 1][j] = *(const short8*)(Wf + (long long)(ubase[j] + step + 1) * 512 + lane * 8);
        }
        short8 af[4];
        #pragma unroll
        for (int m = 0; m < 4; ++m) {
            int row = m * 16 + l15;
            int ch  = (k4 * 4 + lhi) ^ (row & 7);
            af[m] = *(const short8*)&As[((p * 64 + row) * 16 + ch) * 8];
        }
        #pragma unroll
        for (int j = 0; j < 5; ++j) {
            if (usc[j] >= p) {   // wave-uniform branch; -1 sentinel never passes
                #pragma unroll
                for (int m = 0; m < 4; ++m)
                    acc[j][m] = __builtin_amdgcn_mfma_f32_16x16x32_bf16(af[m], bf[cur][j], acc[j][m], 0, 0, 0);
            }
        }
    }

    // epilogue: per scale, deposit to LDS then store coalesced full rows
    #pragma unroll 1
    for (int sc = 0; sc < 3; ++sc) {
        __syncthreads();
        const float* bias = (sc == 0) ? b1 : ((sc == 1) ? b2 : b3);
        #pragma unroll
        for (int j = 0; j < 5; ++j) {
            if (usc[j] == sc) {
                int col = ucol0[j] + l15;
                if (col < FOUT) {
                    float bv = bias[col];
                    #pragma unroll
                    for (int m = 0; m < 4; ++m) {
                        int rbase = m * 16 + lhi * 4;
                        #pragma unroll
                        for (int jj = 0; jj < 4; ++jj)
                            Ef[(rbase + jj) * EPAD + col] = acc[j][m][jj] + bv;
                    }
                }
            }
        }
        __syncthreads();
        float* op = out + (long long)sc * NN * FOUT;
        for (int c = tid; c < 3200; c += 512) {   // 64 rows x 50 f32x4 chunks
            int r = c / 50, pos = c % 50;
            int row = b0 + r;
            if (row < NN) {
                f32x4 v = *(const f32x4*)&Ef[r * EPAD + pos * 4];
                *(f32x4*)&op[(long long)row * FOUT + pos * 4] = v;
            }
        }
    }
}

extern "C" void kernel_launch(void* const* d_in, const int* in_sizes, int n_in,
                              void* d_out, int out_size, void* d_ws, size_t ws_size,
                              hipStream_t stream) {
    const float* x  = (const float*)d_in[0];
    const void*  ei = d_in[1];
    const float* ew = (const float*)d_in[2];
    const float* W1 = (const float*)d_in[3];
    const float* b1 = (const float*)d_in[4];
    const float* W2 = (const float*)d_in[5];
    const float* b2 = (const float*)d_in[6];
    const float* W3 = (const float*)d_in[7];
    const float* b3 = (const float*)d_in[8];
    float* out = (float*)d_out;

    char* ws = (char*)d_ws;
    // layout (bytes):
    // [0,16)                  flag          } zeroed
    // [16, 3200016)           cnt8 8xN i32  } zeroed
    // [3200016, 3600016)      cnt  N i32
    // [3600016, 4000032)      rowstart N+1 (padded)
    // [4000032, 4002080)      bsum 512
    // [4002080, 4402080)      dis  N f32
    // [4402080, 17202080)     edge int2 E
    // [17202080, 42826656)    Xb  bf16 NROWP*128
    // [42826656, 68451232)    T1b bf16
    // [68451232, 94075808)    T2b bf16
    // [94075808, 94395296)    Wf  bf16 frags (312 KB)
    int*   flag     = (int*)(ws + 0);
    int*   cnt8     = (int*)(ws + 16);
    int*   cnt      = (int*)(ws + 3200016);
    int*   rowstart = (int*)(ws + 3600016);
    int*   bsum     = (int*)(ws + 4000032);
    float* dis      = (float*)(ws + 4002080);
    int2*  edge     = (int2*)(ws + 4402080);
    unsigned short* Xb  = (unsigned short*)(ws + 17202080);
    unsigned short* T1b = (unsigned short*)(ws + 42826656);
    unsigned short* T2b = (unsigned short*)(ws + 68451232);
    short* Wf       = (short*)(ws + 94075808);

    hipMemsetAsync(d_ws, 0, 3200016, stream);   // flag + cnt8

    detect_kernel<<<16, 256, 0, stream>>>((const long long*)ei, flag);
    x2bf_kernel<<<6250, 256, 0, stream>>>(x, Xb);
    cnt8_kernel<<<NE / 256, 256, 0, stream>>>(ei, flag, cnt8);
    xreduce<<<NBLK, 256, 0, stream>>>(cnt8, cnt);
    scan_block<<<NBLK, 256, 0, stream>>>(cnt, rowstart, bsum);
    scan_bsums<<<1, 512, 0, stream>>>(bsum);
    scan_add<<<NBLK + 1, 256, 0, stream>>>(rowstart, bsum);
    fill_csr<<<NE / 256, 256, 0, stream>>>(ei, flag, ew, rowstart, cnt8, edge);
    deg_seg<<<NBLK, 256, 0, stream>>>(rowstart, edge, dis);
    gather_prop<0><<<NN / 4, 256, 0, stream>>>(rowstart, edge, dis, Xb, nullptr, T1b);
    gather_prop<1><<<NN / 4, 256, 0, stream>>>(rowstart, edge, dis, T1b, Xb, T2b);
    wprep_frag<<<24, 256, 0, stream>>>(W1, W2, W3, Wf);
    gemm_fused<<<1563, 512, 0, stream>>>(Xb, T1b, T2b, Wf, b1, b2, b3, out);
}